// Round 5
// baseline (4914.930 us; speedup 1.0000x reference)
//
#include <hip/hip_runtime.h>
#include <hip/hip_bf16.h>
#include <type_traits>

typedef __hip_bfloat16 bf16;

// B=4, L=4096, D=1024, H=4, DK=256, C=64, NC=64, KS=4
// Harness dtypes: ALL inputs fp32 (per reference setup_inputs), output fp32.
// Internal workspace intermediates: bf16 (2% absmax threshold gives headroom).

__device__ __forceinline__ float sigmoidf_(float x) { return 1.0f / (1.0f + __expf(-x)); }

__device__ __forceinline__ float bu2f(unsigned short u) {
    return __uint_as_float(((unsigned)u) << 16);
}
__device__ __forceinline__ float2 bu2f2(const unsigned short* p) {
    ushort2 t = *(const ushort2*)p;
    float2 r; r.x = bu2f(t.x); r.y = bu2f(t.y); return r;
}
__device__ __forceinline__ float4 ld4(const float* p) { return *(const float4*)p; }
__device__ __forceinline__ float4 ld4(const bf16* p) {
    ushort4 u = *(const ushort4*)p;
    float4 r;
    r.x = bu2f(u.x); r.y = bu2f(u.y); r.z = bu2f(u.z); r.w = bu2f(u.w);
    return r;
}
__device__ __forceinline__ unsigned short f2bu(float x) {
    bf16 h = __float2bfloat16(x);
    return *reinterpret_cast<unsigned short*>(&h);
}
__device__ __forceinline__ void st4(bf16* p, float a, float b, float c, float d) {
    ushort4 u = { f2bu(a), f2bu(b), f2bu(c), f2bu(d) };
    *(ushort4*)p = u;
}
__device__ __forceinline__ float b2f(bf16 h) { return __bfloat162float(h); }

// ---------------------------------------------------------------------------
// Tiled GEMM: C[M,N] = A[M,K] @ B[K,N].  A: fp32 or bf16; B: fp32; C: bf16 or
// fp32.  64x64 tile, 256 threads, 4x4 per thread.  Optionally batched.
// ---------------------------------------------------------------------------
template <typename InT, typename OutT>
__global__ __launch_bounds__(256)
void gemm_kernel(const InT* __restrict__ A, const float* __restrict__ Bm,
                 OutT* __restrict__ Cm, int M, int N, int K,
                 size_t aStride, size_t bStride, size_t cStride, int hMask)
{
    __shared__ float As[16][68];
    __shared__ float Bs[16][68];
    const int z = blockIdx.z;
    A  += (size_t)z * aStride;
    Bm += (size_t)(z & hMask) * bStride;
    Cm += (size_t)z * cStride;
    const int tid = threadIdx.x;
    const int m0 = blockIdx.y * 64, n0 = blockIdx.x * 64;
    const int ty = tid >> 4, tx = tid & 15;
    const int lAr = tid >> 2, lAk = (tid & 3) << 2;
    const int lBk = tid >> 4, lBn = (tid & 15) << 2;
    float acc[4][4] = {};
    for (int k0 = 0; k0 < K; k0 += 16) {
        float4 a4 = ld4(&A[(size_t)(m0 + lAr) * K + (k0 + lAk)]);
        float4 b4 = *(const float4*)&Bm[(size_t)(k0 + lBk) * N + (n0 + lBn)];
        As[lAk + 0][lAr] = a4.x; As[lAk + 1][lAr] = a4.y;
        As[lAk + 2][lAr] = a4.z; As[lAk + 3][lAr] = a4.w;
        *(float4*)&Bs[lBk][lBn] = b4;
        __syncthreads();
#pragma unroll
        for (int kk = 0; kk < 16; ++kk) {
            float4 av = *(const float4*)&As[kk][ty << 2];
            float4 bv = *(const float4*)&Bs[kk][tx << 2];
            float a_[4] = {av.x, av.y, av.z, av.w};
            float b_[4] = {bv.x, bv.y, bv.z, bv.w};
#pragma unroll
            for (int i = 0; i < 4; ++i)
#pragma unroll
                for (int j = 0; j < 4; ++j)
                    acc[i][j] += a_[i] * b_[j];
        }
        __syncthreads();
    }
#pragma unroll
    for (int i = 0; i < 4; ++i) {
        size_t row = (size_t)(m0 + (ty << 2) + i) * N + n0 + (tx << 2);
        if constexpr (std::is_same<OutT, float>::value) {
            float4 o4 = {acc[i][0], acc[i][1], acc[i][2], acc[i][3]};
            *(float4*)&Cm[row] = o4;
        } else {
            st4(&Cm[row], acc[i][0], acc[i][1], acc[i][2], acc[i][3]);
        }
    }
}

// ---------------------------------------------------------------------------
// Depthwise conv (taps x[t-2+j], j=0..3) + SiLU + optional per-head l2norm.
// In: (B,L,D) bf16 (internal). Out: chunked (B*H, L, DK) bf16.
// ---------------------------------------------------------------------------
__global__ __launch_bounds__(256)
void conv_kernel(const bf16* __restrict__ xin, const float* __restrict__ cw,
                 bf16* __restrict__ outc, int doNorm)
{
    const int bt = blockIdx.x;
    const int b = bt >> 12, t = bt & 4095;
    const int tid = threadIdx.x;
    const int h = tid >> 6, lane = tid & 63;
    const int i0 = lane << 2;
    const int d = (h << 8) + i0;
    float w0[4], w1[4], w2[4], w3[4];
    {
        float4 c0 = *(const float4*)&cw[(d + 0) * 4];
        float4 c1 = *(const float4*)&cw[(d + 1) * 4];
        float4 c2 = *(const float4*)&cw[(d + 2) * 4];
        float4 c3 = *(const float4*)&cw[(d + 3) * 4];
        w0[0] = c0.x; w0[1] = c0.y; w0[2] = c0.z; w0[3] = c0.w;
        w1[0] = c1.x; w1[1] = c1.y; w1[2] = c1.z; w1[3] = c1.w;
        w2[0] = c2.x; w2[1] = c2.y; w2[2] = c2.z; w2[3] = c2.w;
        w3[0] = c3.x; w3[1] = c3.y; w3[2] = c3.z; w3[3] = c3.w;
    }
    float acc[4] = {0.f, 0.f, 0.f, 0.f};
#pragma unroll
    for (int jj = 0; jj < 4; ++jj) {
        int tt = t - 2 + jj;
        if (tt >= 0 && tt < 4096) {
            float4 xr = ld4(&xin[((size_t)(b << 12) + tt) * 1024 + d]);
            acc[0] += xr.x * w0[jj];
            acc[1] += xr.y * w1[jj];
            acc[2] += xr.z * w2[jj];
            acc[3] += xr.w * w3[jj];
        }
    }
#pragma unroll
    for (int j = 0; j < 4; ++j) acc[j] *= sigmoidf_(acc[j]);
    if (doNorm) {
        float ss = acc[0]*acc[0] + acc[1]*acc[1] + acc[2]*acc[2] + acc[3]*acc[3];
#pragma unroll
        for (int off = 32; off > 0; off >>= 1) ss += __shfl_xor(ss, off);
        float r = rsqrtf(ss + 1e-6f);
        acc[0] *= r; acc[1] *= r; acc[2] *= r; acc[3] *= r;
    }
    st4(&outc[(((size_t)((b << 2) + h)) * 4096 + t) * 256 + i0],
        acc[0], acc[1], acc[2], acc[3]);
}

// ---------------------------------------------------------------------------
// beta = sigmoid(x @ Wb), stored (B*H, L) fp32.  x is fp32 input.
// ---------------------------------------------------------------------------
__global__ __launch_bounds__(256)
void beta_kernel(const float* __restrict__ x, const float* __restrict__ Wb,
                 float* __restrict__ beta)
{
    const int bt = blockIdx.x;
    const int b = bt >> 12, t = bt & 4095;
    const int tid = threadIdx.x;
    const int wv = tid >> 6;
    __shared__ float redB[4][4];
    float4 xv = *(const float4*)&x[(size_t)bt * 1024 + (tid << 2)];
    float xa[4] = {xv.x, xv.y, xv.z, xv.w};
    float a[4] = {0.f, 0.f, 0.f, 0.f};
#pragma unroll
    for (int j = 0; j < 4; ++j) {
        float4 wr = *(const float4*)&Wb[((tid << 2) + j) * 4];
        a[0] += xa[j] * wr.x; a[1] += xa[j] * wr.y;
        a[2] += xa[j] * wr.z; a[3] += xa[j] * wr.w;
    }
#pragma unroll
    for (int hh = 0; hh < 4; ++hh)
#pragma unroll
        for (int off = 32; off > 0; off >>= 1) a[hh] += __shfl_xor(a[hh], off);
    if ((tid & 63) == 0) {
        redB[wv][0] = a[0]; redB[wv][1] = a[1]; redB[wv][2] = a[2]; redB[wv][3] = a[3];
    }
    __syncthreads();
    if (tid < 4) {
        float s = redB[0][tid] + redB[1][tid] + redB[2][tid] + redB[3][tid];
        beta[((size_t)((b << 2) + tid)) * 4096 + t] = sigmoidf_(s);
    }
}

// ---------------------------------------------------------------------------
// Per-chunk kernel. NO __restrict__ (kprojG aliases wOut). Static LDS 54.8KB.
// Triangular solves per-thread in registers (thread = one v-column).
// ---------------------------------------------------------------------------
#define KLS 262
#define AST 68
__global__ __launch_bounds__(256)
void chunk_kernel(const bf16* kG, const bf16* vG,
                  const bf16* qG, const float* betaG,
                  const bf16* kprojG,
                  const float* fw1, const float* fb1,
                  const float* fw2, const float* fb2,
                  const float* tempG,
                  bf16* uOut, bf16* wOut,
                  bf16* attnOut, float* psiOut)
{
    __shared__ unsigned short kLs[64 * KLS];   // 33,536 B
    __shared__ float Abuf[64 * AST];           // 17,408 B (reused as q tile)
    __shared__ float betaL[64];
    __shared__ float fluxL[648];
    __shared__ float redL[256];

    const int chunk = blockIdx.x;
    const int bh = chunk >> 6;
    const int n  = chunk & 63;
    const int h  = bh & 3;
    const int tid = threadIdx.x;
    const int wv = tid >> 6, lane = tid & 63;
    const size_t base = ((size_t)bh * 4096 + n * 64) * 256;

    // stage k -> LDS (bf16)
    for (int r = 0; r < 16; ++r) {
        int e4 = r * 256 + tid;
        int c = e4 >> 6, dd = (e4 & 63) << 2;
        ushort4 kv = *(const ushort4*)&kG[base + c * 256 + dd];
        unsigned short* dst = &kLs[c * KLS + dd];
        dst[0] = kv.x; dst[1] = kv.y; dst[2] = kv.z; dst[3] = kv.w;
    }
    if (tid < 64) betaL[tid] = betaG[(size_t)bh * 4096 + n * 64 + tid];
    __syncthreads();

    // A[c][e] = beta_c * (k_c . k_e) for e<c, else 0
    for (int it = 0; it < 16; ++it) {
        int c = it * 4 + wv, e = lane;
        float dot = 0.f;
        if (e < c) {
            const unsigned short* kc = &kLs[c * KLS];
            const unsigned short* ke = &kLs[e * KLS];
            for (int d0 = 0; d0 < 256; d0 += 2) {
                float2 a = bu2f2(kc + d0);
                float2 b = bu2f2(ke + d0);
                dot += a.x * b.x + a.y * b.y;
            }
            dot *= betaL[c];
        }
        Abuf[c * AST + e] = (e < c) ? dot : 0.f;
    }
    __syncthreads();

    // ---- u solve: (I+A) u = beta*v, per-thread column in registers ----
    float ur[64];
#pragma unroll
    for (int c = 0; c < 64; ++c)
        ur[c] = betaL[c] * b2f(vG[base + c * 256 + tid]);
#pragma unroll
    for (int c = 1; c < 64; ++c) {
        float s = 0.f;
        const int G = (c + 3) >> 2;
#pragma unroll
        for (int g = 0; g < G; ++g) {
            float4 a4 = *(const float4*)&Abuf[c * AST + (g << 2)];
            s += a4.x * ur[(g << 2) + 0] + a4.y * ur[(g << 2) + 1]
               + a4.z * ur[(g << 2) + 2] + a4.w * ur[(g << 2) + 3];
        }
        ur[c] -= s;
    }
    // write u + flux partials
    float um = 0.f, accv = 0.f, km = 0.f;
#pragma unroll
    for (int c = 0; c < 64; ++c) {
        uOut[base + c * 256 + tid] = __float2bfloat16(ur[c]);
        um += ur[c];
        accv += b2f(kprojG[base + c * 256 + tid]) * ur[c];
        km += bu2f(kLs[c * KLS + tid]);
    }
    fluxL[tid]       = km * (1.f / 64.f);
    fluxL[256 + tid] = um * (1.f / 64.f);
    redL[tid] = accv;
    __syncthreads();
    for (int s2 = 128; s2 > 0; s2 >>= 1) {
        if (tid < s2) redL[tid] += redL[tid + s2];
        __syncthreads();
    }
    if (tid == 0) fluxL[512] = redL[0] * (1.f / 64.f) / tempG[h];
    __syncthreads();
    // flux MLP -> psi
    if (tid < 128) {
        float a = fb1[tid];
        for (int i2 = 0; i2 < 513; ++i2) a += fluxL[i2] * fw1[i2 * 128 + tid];
        a *= sigmoidf_(a);
        fluxL[520 + tid] = a;
    }
    __syncthreads();
    if (tid < 64) {
        float p = fluxL[520 + tid] * fw2[tid] + fluxL[520 + 64 + tid] * fw2[64 + tid];
#pragma unroll
        for (int off = 32; off > 0; off >>= 1) p += __shfl_xor(p, off);
        if (tid == 0) {
            float ps = sigmoidf_(p + fb2[0]);
            psiOut[chunk] = fminf(0.99f, fmaxf(0.01f, ps));
        }
    }

    // ---- w solve: (I+A) w = beta*k ----
    float wr_[64];
#pragma unroll
    for (int c = 0; c < 64; ++c)
        wr_[c] = betaL[c] * bu2f(kLs[c * KLS + tid]);
#pragma unroll
    for (int c = 1; c < 64; ++c) {
        float s = 0.f;
        const int G = (c + 3) >> 2;
#pragma unroll
        for (int g = 0; g < G; ++g) {
            float4 a4 = *(const float4*)&Abuf[c * AST + (g << 2)];
            s += a4.x * wr_[(g << 2) + 0] + a4.y * wr_[(g << 2) + 1]
               + a4.z * wr_[(g << 2) + 2] + a4.w * wr_[(g << 2) + 3];
        }
        wr_[c] -= s;
    }
#pragma unroll
    for (int c = 0; c < 64; ++c)
        wOut[base + c * 256 + tid] = __float2bfloat16(wr_[c]);

    // ---- attn = tril(q k^T), q staged in 32-row halves over Abuf ----
    unsigned short* qLs = (unsigned short*)Abuf;   // [32][KLS]
    const size_t abase = (size_t)chunk * 4096;
    for (int hh = 0; hh < 2; ++hh) {
        __syncthreads();
        for (int r = 0; r < 8; ++r) {
            int e4 = r * 256 + tid;
            int rr = e4 >> 6, dd = (e4 & 63) << 2;
            ushort4 qv = *(const ushort4*)&qG[base + (hh * 32 + rr) * 256 + dd];
            unsigned short* dst = &qLs[rr * KLS + dd];
            dst[0] = qv.x; dst[1] = qv.y; dst[2] = qv.z; dst[3] = qv.w;
        }
        __syncthreads();
        for (int it = 0; it < 8; ++it) {
            int cl = it * 4 + wv;
            int c = hh * 32 + cl, e = lane;
            float dot = 0.f;
            if (e <= c) {
                const unsigned short* qc = &qLs[cl * KLS];
                const unsigned short* ke = &kLs[e * KLS];
                for (int d0 = 0; d0 < 256; d0 += 2) {
                    float2 a = bu2f2(qc + d0);
                    float2 b = bu2f2(ke + d0);
                    dot += a.x * b.x + a.y * b.y;
                }
            }
            attnOut[abase + c * 64 + e] = __float2bfloat16((e <= c) ? dot : 0.f);
        }
    }
}

// ---------------------------------------------------------------------------
// Sequential scan over 64 chunks. One block per (b,h,vslab16).
// S_fast/S_slow in registers; static LDS 64,000 B.
// ---------------------------------------------------------------------------
#define WQS 262
__global__ __launch_bounds__(256)
void scan_kernel(const bf16* __restrict__ qG, const bf16* __restrict__ kG,
                 const bf16* __restrict__ wG, const bf16* __restrict__ uG,
                 const bf16* __restrict__ attnG, const float* __restrict__ psiG,
                 const float* __restrict__ lamF, const float* __restrict__ lamS,
                 bf16* __restrict__ oG)
{
    __shared__ float Ssum[16 * 260];            // 16,640 B  [v][d]
    __shared__ unsigned short wqk[64 * WQS];    // 33,536 B  (w, then q, then k)
    __shared__ float uiL[64 * 20];              //  5,120 B  [c][v]
    __shared__ unsigned short attnL[64 * 68];   //  8,704 B

    const int bidx = blockIdx.x;
    const int bh = bidx >> 4, vb = bidx & 15;
    const int h = bh & 3;
    const int v0 = vb << 4;
    const int tid = threadIdx.x;
    const int wv = tid >> 6, lane = tid & 63;
    const int vloc = tid & 15, dg = tid >> 4;
    const float lf = lamF[h], ls = lamS[h];

    float Sfr[16], Ssr[16];
#pragma unroll
    for (int j = 0; j < 16; ++j) { Sfr[j] = 0.f; Ssr[j] = 0.f; }

    const size_t bhbase = (size_t)bh * 4096 * 256;
    for (int n = 0; n < 64; ++n) {
        const size_t base = bhbase + (size_t)n * 64 * 256;
        // 1. Ssum[v][d] = Sf + Ss (pre-update state)
#pragma unroll
        for (int j4 = 0; j4 < 4; ++j4) {
            float4 s4;
            s4.x = Sfr[(j4 << 2) + 0] + Ssr[(j4 << 2) + 0];
            s4.y = Sfr[(j4 << 2) + 1] + Ssr[(j4 << 2) + 1];
            s4.z = Sfr[(j4 << 2) + 2] + Ssr[(j4 << 2) + 2];
            s4.w = Sfr[(j4 << 2) + 3] + Ssr[(j4 << 2) + 3];
            *(float4*)&Ssum[vloc * 260 + (dg << 4) + (j4 << 2)] = s4;
        }
        // 2. stage w
        for (int r = 0; r < 16; ++r) {
            int e4 = r * 256 + tid;
            int c = e4 >> 6, dd = (e4 & 63) << 2;
            ushort4 t = *(const ushort4*)&wG[base + c * 256 + dd];
            unsigned short* dst = &wqk[c * WQS + dd];
            dst[0] = t.x; dst[1] = t.y; dst[2] = t.z; dst[3] = t.w;
        }
        // 3. stage u slab (fp32)
        {
            int c = tid >> 2, dd = (tid & 3) << 2;
            ushort4 t = *(const ushort4*)&uG[base + c * 256 + v0 + dd];
            float* dst = &uiL[c * 20 + dd];
            dst[0] = bu2f(t.x); dst[1] = bu2f(t.y);
            dst[2] = bu2f(t.z); dst[3] = bu2f(t.w);
        }
        // 4. stage attn
        {
            const size_t ab = (size_t)(bh * 64 + n) * 4096;
            for (int r = 0; r < 4; ++r) {
                int e4 = r * 256 + tid;
                int c = e4 >> 4, ee = (e4 & 15) << 2;
                ushort4 t = *(const ushort4*)&attnG[ab + c * 64 + ee];
                *(ushort4*)&attnL[c * 68 + ee] = t;
            }
        }
        const float p = psiG[bh * 64 + n];
        __syncthreads();
        // 6. u_i = u - w @ S
        {
            const int c = lane;
            const unsigned short* wrow = &wqk[c * WQS];
            const float* s0 = &Ssum[((wv << 2) + 0) * 260];
            const float* s1 = &Ssum[((wv << 2) + 1) * 260];
            const float* s2 = &Ssum[((wv << 2) + 2) * 260];
            const float* s3 = &Ssum[((wv << 2) + 3) * 260];
            float a0 = 0.f, a1 = 0.f, a2 = 0.f, a3 = 0.f;
            for (int d0 = 0; d0 < 256; d0 += 4) {
                float2 wa = bu2f2(wrow + d0);
                float2 wb = bu2f2(wrow + d0 + 2);
                float4 x0 = *(const float4*)&s0[d0];
                float4 x1 = *(const float4*)&s1[d0];
                float4 x2 = *(const float4*)&s2[d0];
                float4 x3 = *(const float4*)&s3[d0];
                a0 += wa.x * x0.x + wa.y * x0.y + wb.x * x0.z + wb.y * x0.w;
                a1 += wa.x * x1.x + wa.y * x1.y + wb.x * x1.z + wb.y * x1.w;
                a2 += wa.x * x2.x + wa.y * x2.y + wb.x * x2.z + wb.y * x2.w;
                a3 += wa.x * x3.x + wa.y * x3.y + wb.x * x3.z + wb.y * x3.w;
            }
            int ub = c * 20 + (wv << 2);
            uiL[ub + 0] -= a0; uiL[ub + 1] -= a1;
            uiL[ub + 2] -= a2; uiL[ub + 3] -= a3;
        }
        __syncthreads();
        // 7. stage q
        for (int r = 0; r < 16; ++r) {
            int e4 = r * 256 + tid;
            int c = e4 >> 6, dd = (e4 & 63) << 2;
            ushort4 t = *(const ushort4*)&qG[base + c * 256 + dd];
            unsigned short* dst = &wqk[c * WQS + dd];
            dst[0] = t.x; dst[1] = t.y; dst[2] = t.z; dst[3] = t.w;
        }
        __syncthreads();
        // 8. o = q @ S + attn @ u_i
        {
            const int c = lane;
            const unsigned short* qrow = &wqk[c * WQS];
            const float* s0 = &Ssum[((wv << 2) + 0) * 260];
            const float* s1 = &Ssum[((wv << 2) + 1) * 260];
            const float* s2 = &Ssum[((wv << 2) + 2) * 260];
            const float* s3 = &Ssum[((wv << 2) + 3) * 260];
            float a0 = 0.f, a1 = 0.f, a2 = 0.f, a3 = 0.f;
            for (int d0 = 0; d0 < 256; d0 += 4) {
                float2 qa = bu2f2(qrow + d0);
                float2 qb = bu2f2(qrow + d0 + 2);
                float4 x0 = *(const float4*)&s0[d0];
                float4 x1 = *(const float4*)&s1[d0];
                float4 x2 = *(const float4*)&s2[d0];
                float4 x3 = *(const float4*)&s3[d0];
                a0 += qa.x * x0.x + qa.y * x0.y + qb.x * x0.z + qb.y * x0.w;
                a1 += qa.x * x1.x + qa.y * x1.y + qb.x * x1.z + qb.y * x1.w;
                a2 += qa.x * x2.x + qa.y * x2.y + qb.x * x2.z + qb.y * x2.w;
                a3 += qa.x * x3.x + qa.y * x3.y + qb.x * x3.z + qb.y * x3.w;
            }
            const unsigned short* ar = &attnL[c * 68];
            for (int e = 0; e < 64; ++e) {
                float av = bu2f(ar[e]);
                const float* ue = &uiL[e * 20 + (wv << 2)];
                a0 += av * ue[0]; a1 += av * ue[1];
                a2 += av * ue[2]; a3 += av * ue[3];
            }
            st4(&oG[base + c * 256 + v0 + (wv << 2)], a0, a1, a2, a3);
        }
        __syncthreads();
        // 9. stage k
        for (int r = 0; r < 16; ++r) {
            int e4 = r * 256 + tid;
            int c = e4 >> 6, dd = (e4 & 63) << 2;
            ushort4 t = *(const ushort4*)&kG[base + c * 256 + dd];
            unsigned short* dst = &wqk[c * WQS + dd];
            dst[0] = t.x; dst[1] = t.y; dst[2] = t.z; dst[3] = t.w;
        }
        __syncthreads();
        // 10. dS = k^T u_i ; register state update
        {
            float ur[64];
#pragma unroll
            for (int c = 0; c < 64; ++c) ur[c] = uiL[c * 20 + vloc];
#pragma unroll
            for (int j = 0; j < 16; j += 2) {
                float ax = 0.f, ay = 0.f;
                for (int c = 0; c < 64; ++c) {
                    float2 kv = bu2f2(&wqk[c * WQS + (dg << 4) + j]);
                    ax += kv.x * ur[c]; ay += kv.y * ur[c];
                }
                Sfr[j]     = lf * Sfr[j]     + p * ax;
                Sfr[j + 1] = lf * Sfr[j + 1] + p * ay;
                Ssr[j]     = ls * Ssr[j]     + (1.f - p) * ax;
                Ssr[j + 1] = ls * Ssr[j + 1] + (1.f - p) * ay;
            }
        }
        __syncthreads();
    }
}

// ---------------------------------------------------------------------------
// Final RMSNorm * rms_w * sigmoid(g): chunked o -> natural (B,L,D) bf16
// ---------------------------------------------------------------------------
__global__ __launch_bounds__(256)
void fnorm_kernel(const bf16* __restrict__ oS, const bf16* __restrict__ xg,
                  const float* __restrict__ rmsw, bf16* __restrict__ outn)
{
    const int bt = blockIdx.x;
    const int b = bt >> 12, t = bt & 4095;
    const int tid = threadIdx.x;
    const int h = tid >> 6, lane = tid & 63;
    const int i0 = lane << 2;
    float4 o4 = ld4(&oS[(((size_t)((b << 2) + h)) * 4096 + t) * 256 + i0]);
    float ss = o4.x * o4.x + o4.y * o4.y + o4.z * o4.z + o4.w * o4.w;
#pragma unroll
    for (int off = 32; off > 0; off >>= 1) ss += __shfl_xor(ss, off);
    float r = rsqrtf(ss * (1.f / 256.f) + 1e-5f);
    float4 g4 = ld4(&xg[(size_t)bt * 1024 + (h << 8) + i0]);
    float4 w4 = *(const float4*)&rmsw[i0];
    st4(&outn[(size_t)bt * 1024 + (h << 8) + i0],
        o4.x * r * w4.x * sigmoidf_(g4.x),
        o4.y * r * w4.y * sigmoidf_(g4.y),
        o4.z * r * w4.z * sigmoidf_(g4.z),
        o4.w * r * w4.w * sigmoidf_(g4.w));
}

// ---------------------------------------------------------------------------
extern "C" void kernel_launch(void* const* d_in, const int* in_sizes, int n_in,
                              void* d_out, int out_size, void* d_ws, size_t ws_size,
                              hipStream_t stream)
{
    const float* x    = (const float*)d_in[0];
    const float* Wq   = (const float*)d_in[1];
    const float* Wk   = (const float*)d_in[2];
    const float* Wv   = (const float*)d_in[3];
    const float* Wb   = (const float*)d_in[4];
    const float* Wg   = (const float*)d_in[5];
    const float* Wo   = (const float*)d_in[6];
    const float* cq   = (const float*)d_in[7];
    const float* ck   = (const float*)d_in[8];
    const float* cv   = (const float*)d_in[9];
    const float* Wbil = (const float*)d_in[10];
    const float* temp = (const float*)d_in[11];
    const float* fw1  = (const float*)d_in[12];
    const float* fb1  = (const float*)d_in[13];
    const float* fw2  = (const float*)d_in[14];
    const float* fb2  = (const float*)d_in[15];
    const float* rmsw = (const float*)d_in[16];
    const float* lamF = (const float*)d_in[17];
    const float* lamS = (const float*)d_in[18];
    float* out = (float*)d_out;   // fp32 output, per reference dtype

    const size_t SZ = 16777216ull;             // elems per (B,H,L,DK) slab
    bf16* bws = (bf16*)d_ws;
    bf16* S0 = bws;                            // proj scratch -> g
    bf16* S1 = bws + SZ;                       // q -> onorm
    bf16* S2 = bws + 2 * SZ;                   // k
    bf16* S3 = bws + 3 * SZ;                   // v -> o
    bf16* S4 = bws + 4 * SZ;                   // kproj -> w
    bf16* S5 = bws + 5 * SZ;                   // u
    bf16* attnB = bws + 6 * SZ;                // 4,194,304 elems (8MB)
    float* p_beta = (float*)(bws + 6 * SZ + 4194304);  // 65,536 fp32
    float* p_psi  = p_beta + 65536;            // 1,024 fp32
    // total ~200.3 MB

    dim3 gBig(16, 256, 1);
    gemm_kernel<float, bf16><<<gBig, 256, 0, stream>>>(x, Wq, S0, 16384, 1024, 1024, 0, 0, 0, 0);
    conv_kernel<<<16384, 256, 0, stream>>>(S0, cq, S1, 1);
    gemm_kernel<float, bf16><<<gBig, 256, 0, stream>>>(x, Wk, S0, 16384, 1024, 1024, 0, 0, 0, 0);
    conv_kernel<<<16384, 256, 0, stream>>>(S0, ck, S2, 1);
    gemm_kernel<float, bf16><<<gBig, 256, 0, stream>>>(x, Wv, S0, 16384, 1024, 1024, 0, 0, 0, 0);
    conv_kernel<<<16384, 256, 0, stream>>>(S0, cv, S3, 0);
    gemm_kernel<float, bf16><<<gBig, 256, 0, stream>>>(x, Wg, S0, 16384, 1024, 1024, 0, 0, 0, 0);
    beta_kernel<<<16384, 256, 0, stream>>>(x, Wb, p_beta);
    // kproj = k @ Wbil[h]
    gemm_kernel<bf16, bf16><<<dim3(4, 64, 16), 256, 0, stream>>>(
        S2, Wbil, S4, 4096, 256, 256, 1048576ull, 65536ull, 1048576ull, 3);
    chunk_kernel<<<1024, 256, 0, stream>>>(
        S2, S3, S1, p_beta, S4, fw1, fb1, fw2, fb2, temp,
        S5 /*u*/, S4 /*w*/, attnB, p_psi);
    scan_kernel<<<256, 256, 0, stream>>>(
        S1, S2, S4, S5, attnB, p_psi, lamF, lamS, S3 /*o*/);
    fnorm_kernel<<<16384, 256, 0, stream>>>(S3, S0, rmsw, S1);
    // output projection -> fp32 d_out
    gemm_kernel<bf16, float><<<gBig, 256, 0, stream>>>(S1, Wo, out, 16384, 1024, 1024, 0, 0, 0, 0);
}